// Round 15
// baseline (117.451 us; speedup 1.0000x reference)
//
#include <hip/hip_runtime.h>
#include <stdint.h>

typedef short short8 __attribute__((ext_vector_type(8)));
typedef float f32x4 __attribute__((ext_vector_type(4)));
typedef float f32x16 __attribute__((ext_vector_type(16)));
typedef unsigned int uint2v __attribute__((ext_vector_type(2)));
typedef unsigned int uint4v __attribute__((ext_vector_type(4)));

#define SEQ 2048
#define NBH 32   // B*H

__device__ __forceinline__ unsigned short f32_to_bf16(float f) {
  union { float f; uint32_t u; } v; v.f = f;
  return (unsigned short)((v.u + 0x7fffu + ((v.u >> 16) & 1u)) >> 16);
}

__device__ __forceinline__ float bf16_to_f32(unsigned short u) {
  union { uint32_t u; float f; } v; v.u = ((uint32_t)u) << 16;
  return v.f;
}

__device__ __forceinline__ unsigned int cvtpk_bf16(float lo, float hi) {
  unsigned int r;
  asm("v_cvt_pk_bf16_f32 %0, %1, %2" : "=v"(r) : "v"(lo), "v"(hi));
  return r;
}

__device__ __forceinline__ void gload_lds16(const unsigned short* g, unsigned short* l) {
  __builtin_amdgcn_global_load_lds(
      (const __attribute__((address_space(1))) unsigned int*)g,
      (__attribute__((address_space(3))) unsigned int*)l, 16, 0, 0);
}

// One launch casts x AND all four weight matrices: XB, WQB, WKB, WVB, WOB are
// contiguous in ws, so the destination index is just g.
__global__ void cast_all(const float* __restrict__ x,
                         const float* __restrict__ Wq, const float* __restrict__ Wk,
                         const float* __restrict__ Wv, const float* __restrict__ Wo,
                         unsigned short* __restrict__ ws0) {
  int g = blockIdx.x * blockDim.x + threadIdx.x;   // 0..2097151
  int wi = g >> 18, gl = g & 262143;
  const float* src; int off;
  if (wi < 4)      { src = x;  off = g;  }
  else if (wi == 4){ src = Wq; off = gl; }
  else if (wi == 5){ src = Wk; off = gl; }
  else if (wi == 6){ src = Wv; off = gl; }
  else             { src = Wo; off = gl; }
  float4 v = ((const float4*)src)[off];
  ushort4 o;
  o.x = f32_to_bf16(v.x); o.y = f32_to_bf16(v.y);
  o.z = f32_to_bf16(v.z); o.w = f32_to_bf16(v.w);
  ((ushort4*)ws0)[g] = o;
}

// XOR swizzle over the 4 16B-slots of a 64B LDS row: 2-way max bank conflict
#define GSWZ(row, k) ((k) ^ ((row) & 3) ^ (((row) >> 2) & 3))

// C = A(row-major [M][1024]) * B^T (B row-major [N][1024]), 128x128 tile, BK=32,
// 256 threads = 4 waves (2x2), each wave 64x64 via 4x4 16x16x32 bf16 MFMAs.
__device__ __forceinline__ void gemm_core_1024(
    const unsigned short* __restrict__ Ag,   // pre-offset to tile-row base
    const unsigned short* __restrict__ Bg,   // pre-offset to tile-col base
    int tid, f32x4 acc[4][4])
{
  __shared__ __align__(16) unsigned short As[128 * 32];
  __shared__ __align__(16) unsigned short Bs[128 * 32];
  const int w = tid >> 6, l = tid & 63;
  const int wr = w >> 1, wc = w & 1;
  const int lc = l & 15, lg = l >> 4;

  const int c0row = tid >> 2,        c0ks = tid & 3;   // chunk t=0
  const int c1row = (256 + tid) >> 2;                  // chunk t=1 (same ks)

  for (int k0 = 0; k0 < 1024; k0 += 32) {
    int kg0 = GSWZ(c0row, c0ks);
    int kg1 = GSWZ(c1row, c0ks);
    gload_lds16(Ag + (size_t)c0row * 1024 + k0 + kg0 * 8, As + (w * 64) * 8);
    gload_lds16(Ag + (size_t)c1row * 1024 + k0 + kg1 * 8, As + (256 + w * 64) * 8);
    gload_lds16(Bg + (size_t)c0row * 1024 + k0 + kg0 * 8, Bs + (w * 64) * 8);
    gload_lds16(Bg + (size_t)c1row * 1024 + k0 + kg1 * 8, Bs + (256 + w * 64) * 8);
    __syncthreads();

    short8 a[4], b[4];
#pragma unroll
    for (int mi = 0; mi < 4; ++mi) {
      int row = wr * 64 + mi * 16 + lc;
      int ko = GSWZ(row, lg);
      a[mi] = *(const short8*)(As + row * 32 + ko * 8);
    }
#pragma unroll
    for (int ni = 0; ni < 4; ++ni) {
      int row = wc * 64 + ni * 16 + lc;
      int ko = GSWZ(row, lg);
      b[ni] = *(const short8*)(Bs + row * 32 + ko * 8);
    }
#pragma unroll
    for (int mi = 0; mi < 4; ++mi)
#pragma unroll
      for (int ni = 0; ni < 4; ++ni)
        acc[mi][ni] = __builtin_amdgcn_mfma_f32_16x16x32_bf16(a[mi], b[ni], acc[mi][ni], 0, 0, 0);
    __syncthreads();
  }
}

// QKV GEMM: A = x_bf16 [4096][1024]; B selected among Wq/Wk/Wv by tile col.
// Q: scaled by log2(e)/32, layout [bh][n][64]. K: [bh][n][64].
// V: written DIRECTLY TRANSPOSED to VT [bh][64 d][2048 n] (vectorized 8B stores).
__global__ __launch_bounds__(256, 3)
void gemm_qkv(const unsigned short* __restrict__ XB,
              const unsigned short* __restrict__ WQB,
              const unsigned short* __restrict__ WKB,
              const unsigned short* __restrict__ WVB,
              const float* __restrict__ bq,
              const float* __restrict__ bk,
              const float* __restrict__ bv,
              unsigned short* __restrict__ Qo,
              unsigned short* __restrict__ Ko,
              unsigned short* __restrict__ VTo)
{
  const int tid = threadIdx.x;
  const int tm = blockIdx.x * 128;
  const int tn = blockIdx.y * 128;            // 0..2944
  const int wi = tn >> 10;
  const int tnl = tn & 1023;
  const unsigned short* Bw = (wi == 0 ? WQB : wi == 1 ? WKB : WVB) + (size_t)tnl * 1024;
  const float* bias = (wi == 0 ? bq : wi == 1 ? bk : bv);
  const float qscale = (wi == 0) ? 0.04508422002778011f : 1.0f;  // log2(e)/32

  f32x4 acc[4][4];
#pragma unroll
  for (int mi = 0; mi < 4; ++mi)
#pragma unroll
    for (int ni = 0; ni < 4; ++ni)
      acc[mi][ni] = (f32x4){0.f, 0.f, 0.f, 0.f};

  gemm_core_1024(XB + (size_t)tm * 1024, Bw, tid, acc);

  const int w = tid >> 6, l = tid & 63;
  const int wr = w >> 1, wc = w & 1;
  const int lc = l & 15, lg = l >> 4;

  if (wi == 2) {
    // V transposed epilogue: 4 consecutive i (r=0..3) pack into one 8B store.
#pragma unroll
    for (int ni = 0; ni < 4; ++ni) {
      int nl = tnl + wc * 64 + ni * 16 + lc;
      float bb = bias[nl];
      int h = nl >> 6, d = nl & 63;
#pragma unroll
      for (int mi = 0; mi < 4; ++mi) {
        int ibase = tm + wr * 64 + mi * 16 + lg * 4;
        int b = ibase >> 11, i = ibase & 2047;
        uint2v pk;
        pk.x = cvtpk_bf16(acc[mi][ni][0] + bb, acc[mi][ni][1] + bb);
        pk.y = cvtpk_bf16(acc[mi][ni][2] + bb, acc[mi][ni][3] + bb);
        *(uint2v*)(VTo + (((size_t)(b * 16 + h) * 64 + d) * SEQ + i)) = pk;
      }
    }
  } else {
    unsigned short* Out = (wi == 0) ? Qo : Ko;
#pragma unroll
    for (int ni = 0; ni < 4; ++ni) {
      int nl = tnl + wc * 64 + ni * 16 + lc;
      float bb = bias[nl];
      int h = nl >> 6, d = nl & 63;
#pragma unroll
      for (int mi = 0; mi < 4; ++mi) {
#pragma unroll
        for (int r = 0; r < 4; ++r) {
          int m = tm + wr * 64 + mi * 16 + lg * 4 + r;
          int b = m >> 11, i = m & 2047;
          float v = (acc[mi][ni][r] + bb) * qscale;
          Out[(((size_t)(b * 16 + h) * SEQ + i) << 6) + d] = f32_to_bf16(v);
        }
      }
    }
  }
}

// O GEMM with fused j-split merge + normalize. R14 lesson: the synchronous
// A-path (2 global loads + Lp loads + merge + ds_write) was fully exposed per
// iter at 2 blocks/CU. This version: (a) all 16 inv[h] hoisted to registers
// at kernel entry, (b) T14-lite — next iter's Op0/Op1 loads issued BEFORE the
// first barrier so their latency hides under barrier+fragread+MFMA; vmcnt
// drains naturally at next iter's merge. 64x128 tile, grid 64x8 = 512 blocks.
__global__ __launch_bounds__(256, 2)
void gemm_o_norm(const unsigned short* __restrict__ Op0,
                 const unsigned short* __restrict__ Op1,
                 const float* __restrict__ Lp,
                 const unsigned short* __restrict__ WOB,
                 const float* __restrict__ bo,
                 float* __restrict__ Of)
{
  __shared__ __align__(16) unsigned short As[64 * 32];
  __shared__ __align__(16) unsigned short Bs[128 * 32];
  const int tid = threadIdx.x;
  const int w = tid >> 6, l = tid & 63;
  const int lc = l & 15, lg = l >> 4;
  const int tm = blockIdx.x * 64;
  const int tn = blockIdx.y * 128;
  const unsigned short* Bg = WOB + (size_t)tn * 1024;

  const int crow = tid >> 2, cks = tid & 3;
  const int m = tm + crow;
  const int bb_ = m >> 11, ii = m & 2047;
  const int kg = GSWZ(crow, cks);
  const size_t abase = (size_t)m * 1024 + kg * 8;     // elem offset in Op*
  const float* LpA = Lp + (size_t)(bb_ * 16) * SEQ + ii;   // + h*SEQ
  const float* LpB = LpA + (size_t)NBH * SEQ;

  // hoist all 16 per-head inverses (removes per-iter Lp latency + fdiv)
  float inv[16];
#pragma unroll
  for (int hh = 0; hh < 16; ++hh)
    inv[hh] = 1.0f / (LpA[(size_t)hh * SEQ] + LpB[(size_t)hh * SEQ]);

  union AV { uint4v v; unsigned short e[8]; };
  AV A0, A1, A0n, A1n;
  A0.v = *(const uint4v*)(Op0 + abase);        // preload k0 = 0
  A1.v = *(const uint4v*)(Op1 + abase);

  f32x4 acc[4][2];
#pragma unroll
  for (int mi = 0; mi < 4; ++mi)
#pragma unroll
    for (int ni = 0; ni < 2; ++ni)
      acc[mi][ni] = (f32x4){0.f, 0.f, 0.f, 0.f};

  for (int k0 = 0; k0 < 1024; k0 += 32) {
    // B staging (async)
    gload_lds16(Bg + (size_t)crow * 1024 + k0 + kg * 8, Bs + w * 512);
    gload_lds16(Bg + (size_t)(64 + crow) * 1024 + k0 + kg * 8, Bs + 2048 + w * 512);

    // merge + normalize current A regs, write to swizzled LDS slot
    const float iv = inv[k0 >> 6];
    uint4v wv;
    wv.x = cvtpk_bf16((bf16_to_f32(A0.e[0]) + bf16_to_f32(A1.e[0])) * iv,
                      (bf16_to_f32(A0.e[1]) + bf16_to_f32(A1.e[1])) * iv);
    wv.y = cvtpk_bf16((bf16_to_f32(A0.e[2]) + bf16_to_f32(A1.e[2])) * iv,
                      (bf16_to_f32(A0.e[3]) + bf16_to_f32(A1.e[3])) * iv);
    wv.z = cvtpk_bf16((bf16_to_f32(A0.e[4]) + bf16_to_f32(A1.e[4])) * iv,
                      (bf16_to_f32(A0.e[5]) + bf16_to_f32(A1.e[5])) * iv);
    wv.w = cvtpk_bf16((bf16_to_f32(A0.e[6]) + bf16_to_f32(A1.e[6])) * iv,
                      (bf16_to_f32(A0.e[7]) + bf16_to_f32(A1.e[7])) * iv);
    *(uint4v*)(As + crow * 32 + cks * 8) = wv;

    // T14-lite: issue next iter's A loads now — they complete under the
    // barrier + fragment reads + MFMAs below.
    if (k0 + 32 < 1024) {
      A0n.v = *(const uint4v*)(Op0 + abase + k0 + 32);
      A1n.v = *(const uint4v*)(Op1 + abase + k0 + 32);
    }
    __syncthreads();

    short8 a[4], b[2];
#pragma unroll
    for (int mi = 0; mi < 4; ++mi) {
      int row = mi * 16 + lc;
      a[mi] = *(const short8*)(As + row * 32 + GSWZ(row, lg) * 8);
    }
#pragma unroll
    for (int ni = 0; ni < 2; ++ni) {
      int row = w * 32 + ni * 16 + lc;
      b[ni] = *(const short8*)(Bs + row * 32 + GSWZ(row, lg) * 8);
    }
#pragma unroll
    for (int mi = 0; mi < 4; ++mi)
#pragma unroll
      for (int ni = 0; ni < 2; ++ni)
        acc[mi][ni] = __builtin_amdgcn_mfma_f32_16x16x32_bf16(a[mi], b[ni], acc[mi][ni], 0, 0, 0);
    __syncthreads();
    A0 = A0n; A1 = A1n;
  }

#pragma unroll
  for (int ni = 0; ni < 2; ++ni) {
    int n = tn + w * 32 + ni * 16 + lc;
    float bb = bo[n];
#pragma unroll
    for (int mi = 0; mi < 4; ++mi) {
#pragma unroll
      for (int r = 0; r < 4; ++r) {
        int mm = tm + mi * 16 + lg * 4 + r;
        Of[(size_t)mm * 1024 + n] = acc[mi][ni][r] + bb;
      }
    }
  }
}

// ---------------------------------------------------------------------------
// Flash attention fwd v11 (proven 47.8us; VGPR 64, no spill). Fixed-base
// softmax + j-split, disjoint partial stores; halved pa-build shuffles.
// NOTE: v_permlane32_swap_b32 tried twice (R4/R11) — semantics not as
// modeled; DO NOT USE. __shfl_xor(.,32) is the proven exchange.
// Grid (32 bh, 16 qt, 2 js) = 1024 blocks = 4 blocks/CU = 16 waves/CU.
// ---------------------------------------------------------------------------
__global__ __launch_bounds__(256, 4)
void attn_fwd11(const unsigned short* __restrict__ Qm,
                const unsigned short* __restrict__ Km,
                const unsigned short* __restrict__ VTm,
                unsigned short* __restrict__ Op0,
                unsigned short* __restrict__ Op1,
                float* __restrict__ Lp)
{
  __shared__ __align__(16) unsigned short KV[2][64 * 128];
  const int tid = threadIdx.x, w = tid >> 6, l = tid & 63;
  const int lq = l & 31, hi = l >> 5;
  const int m15 = lq & 15;
  const int bh = blockIdx.x, q0 = blockIdx.y * 128;
  const int js = blockIdx.z;
  const int j0 = js << 10;                   // j-split: 0 or 1024

  const unsigned short* Qb = Qm + ((size_t)bh * SEQ + q0 + w * 32) * 64;
  const unsigned short* Kg = Km + ((size_t)bh * SEQ + j0) * 64;
  const unsigned short* Vg = VTm + (size_t)bh * 64 * SEQ + j0;   // [64 d][j0..]

  // Staging (R3-verified): LDS[r][s] = G[r][s ^ (r&15)], row r = K[j+r]|VT[r].
  const int sr = l >> 4;        // row within 4-row chunk
  const int ss = l & 15;        // 16B slot
  const unsigned short* sp[4];
  int sstep[4];
#pragma unroll
  for (int i = 0; i < 4; ++i) {
    int r = w * 16 + i * 4 + sr;
    int t = ss ^ (i * 4 + sr);                 // (r&15) == i*4+sr
    if (t < 8) { sp[i] = Kg + (size_t)r * 64 + t * 8;          sstep[i] = 64 * 64; }
    else       { sp[i] = Vg + (size_t)r * SEQ + (t - 8) * 8;   sstep[i] = 64; }
  }

  // Q fragments (B-operand): col=q=lane&31, k = d = kc*16 + hi*8 + [0..7]
  short8 qf[4];
#pragma unroll
  for (int kc = 0; kc < 4; ++kc)
    qf[kc] = *(const short8*)(Qb + lq * 64 + kc * 16 + hi * 8);

  f32x16 o0, o1;
#pragma unroll
  for (int r = 0; r < 16; ++r) { o0[r] = 0.f; o1[r] = 0.f; }
  float sm[8];
#pragma unroll
  for (int i = 0; i < 8; ++i) sm[i] = 0.f;

  // prologue: stage tile 0
#pragma unroll
  for (int i = 0; i < 4; ++i) {
    gload_lds16(sp[i], &KV[0][(w * 16 + i * 4) * 128]);
    sp[i] += sstep[i];
  }
  __syncthreads();

  for (int t = 0; t < 16; ++t) {
    const int cur = t & 1;
    if (t + 1 < 16) {
#pragma unroll
      for (int i = 0; i < 4; ++i) {
        gload_lds16(sp[i], &KV[cur ^ 1][(w * 16 + i * 4) * 128]);
        sp[i] += sstep[i];
      }
    }
    const char* Tb = (const char*)(&KV[cur][0]);

    // S^T = K*Q^T (includes /sqrt(f)*log2e): col=q, row=j_local
    f32x16 s0, s1;
#pragma unroll
    for (int r = 0; r < 16; ++r) { s0[r] = 0.f; s1[r] = 0.f; }
    __builtin_amdgcn_s_setprio(1);
#pragma unroll
    for (int kc = 0; kc < 4; ++kc) {
      short8 kf = *(const short8*)(Tb + lq * 256 + (((kc * 2 + hi) ^ m15) << 4));
      s0 = __builtin_amdgcn_mfma_f32_32x32x16_bf16(kf, qf[kc], s0, 0, 0, 0);
    }
#pragma unroll
    for (int kc = 0; kc < 4; ++kc) {
      short8 kf = *(const short8*)(Tb + (32 + lq) * 256 + (((kc * 2 + hi) ^ m15) << 4));
      s1 = __builtin_amdgcn_mfma_f32_32x32x16_bf16(kf, qf[kc], s1, 0, 0, 0);
    }
    __builtin_amdgcn_s_setprio(0);

    // fixed-base softmax: p = 2^s directly (no max, no subtraction)
    float p[32];
#pragma unroll
    for (int r = 0; r < 16; ++r) {
      p[r] = __builtin_amdgcn_exp2f(s0[r]);
      p[16 + r] = __builtin_amdgcn_exp2f(s1[r]);
    }
#pragma unroll
    for (int i = 0; i < 8; ++i)
      sm[i] += (p[i] + p[i + 8]) + (p[i + 16] + p[i + 24]);

    // P -> bf16 B-fragments: pa[ks] holds P[q][ks*16 + hi*8 + 0..7].
    // Halved exchange: send what the partner needs, one shfl per pair.
    short8 pa[4];
#pragma unroll
    for (int ks = 0; ks < 4; ++ks) {
      const int pb = ks * 8;
      unsigned int a0 = cvtpk_bf16(p[pb + 0], p[pb + 1]);
      unsigned int a1 = cvtpk_bf16(p[pb + 2], p[pb + 3]);
      unsigned int b0 = cvtpk_bf16(p[pb + 4], p[pb + 5]);
      unsigned int b1 = cvtpk_bf16(p[pb + 6], p[pb + 7]);
      unsigned int s0v = hi ? a0 : b0;           // partner's need
      unsigned int s1v = hi ? a1 : b1;
      unsigned int r0 = __shfl_xor((int)s0v, 32);
      unsigned int r1 = __shfl_xor((int)s1v, 32);
      union { uint4v u; short8 s; } cvt;
      cvt.u.x = hi ? r0 : a0;   // hi: partner's b0 ; lo: own a0
      cvt.u.y = hi ? r1 : a1;
      cvt.u.z = hi ? b0 : r0;   // hi: own b0 ; lo: partner's a0
      cvt.u.w = hi ? b1 : r1;
      pa[ks] = cvt.s;
    }

    // O^T += VT * P^T: col=q, row=d_local; V slots are 8..15 of each row
    __builtin_amdgcn_s_setprio(1);
#pragma unroll
    for (int ks = 0; ks < 4; ++ks) {
      short8 vf = *(const short8*)(Tb + lq * 256 + (((8 + ks * 2 + hi) ^ m15) << 4));
      o0 = __builtin_amdgcn_mfma_f32_32x32x16_bf16(vf, pa[ks], o0, 0, 0, 0);
    }
#pragma unroll
    for (int ks = 0; ks < 4; ++ks) {
      short8 vf = *(const short8*)(Tb + (32 + lq) * 256 + (((8 + ks * 2 + hi) ^ m15) << 4));
      o1 = __builtin_amdgcn_mfma_f32_32x32x16_bf16(vf, pa[ks], o1, 0, 0, 0);
    }
    __builtin_amdgcn_s_setprio(0);
    __syncthreads();   // drains vmcnt (stage) + lgkm; buffers flip
  }

  // epilogue: vectorized bf16 partial stores into js-private buffer
  float lden = ((sm[0] + sm[1]) + (sm[2] + sm[3])) + ((sm[4] + sm[5]) + (sm[6] + sm[7]));
  lden += __shfl_xor(lden, 32);              // combine hi/lo j-interleave halves
  const int b = bh >> 4, h = bh & 15;
  const int iq = q0 + w * 32 + lq;
  unsigned short* Op = js ? Op1 : Op0;
  if (hi == 0) Lp[(size_t)js * (NBH * SEQ) + (size_t)bh * SEQ + iq] = lden;
  const size_t obase = ((size_t)b * SEQ + iq) * 1024 + h * 64;
#pragma unroll
  for (int rq = 0; rq < 4; ++rq) {
    uint2v pk0, pk1;
    pk0.x = cvtpk_bf16(o0[rq * 4 + 0], o0[rq * 4 + 1]);
    pk0.y = cvtpk_bf16(o0[rq * 4 + 2], o0[rq * 4 + 3]);
    pk1.x = cvtpk_bf16(o1[rq * 4 + 0], o1[rq * 4 + 1]);
    pk1.y = cvtpk_bf16(o1[rq * 4 + 2], o1[rq * 4 + 3]);
    *(uint2v*)(Op + obase + rq * 8 + hi * 4) = pk0;
    *(uint2v*)(Op + obase + 32 + rq * 8 + hi * 4) = pk1;
  }
}

extern "C" void kernel_launch(void* const* d_in, const int* in_sizes, int n_in,
                              void* d_out, int out_size, void* d_ws, size_t ws_size,
                              hipStream_t stream) {
  (void)in_sizes; (void)n_in; (void)out_size; (void)ws_size;
  const float* x  = (const float*)d_in[0];
  const float* Wq = (const float*)d_in[1];
  const float* bq = (const float*)d_in[2];
  const float* Wk = (const float*)d_in[3];
  const float* bk = (const float*)d_in[4];
  const float* Wv = (const float*)d_in[5];
  const float* bv = (const float*)d_in[6];
  const float* Wo = (const float*)d_in[7];
  const float* bo = (const float*)d_in[8];
  float* Of = (float*)d_out;

  // ws layout (bf16-elem offsets); total 58,720,256 bytes.
  // Aliases (dead regions by attn time): Op0 over XB, Op1 right before VTB,
  // Lp over WQB. V is written directly transposed into VTB by gemm_qkv.
  unsigned short* ws  = (unsigned short*)d_ws;
  unsigned short* XB  = ws;               // x bf16 [4096][1024]
  unsigned short* WQB = ws + 4194304u;    // W casts contiguous: WQB,WKB,WVB,WOB
  unsigned short* WKB = ws + 5242880u;
  unsigned short* WVB = ws + 6291456u;
  unsigned short* WOB = ws + 7340032u;
  unsigned short* QB  = ws + 8388608u;    // [32][2048][64]
  unsigned short* KB  = ws + 12582912u;
  unsigned short* VTB = ws + 20971520u;   // [32][64][2048]
  unsigned short* Op0 = ws;               // [4096][1024] bf16 (js=0, over XB)
  unsigned short* Op1 = ws + 16777216u;   // [4096][1024] bf16 (js=1)
  float* Lp = (float*)(ws + 4194304u);    // [2][32][2048] f32 (over WQB)

  cast_all<<<8192, 256, 0, stream>>>(x, Wq, Wk, Wv, Wo, ws);

  gemm_qkv<<<dim3(32, 24), 256, 0, stream>>>(XB, WQB, WKB, WVB, bq, bk, bv, QB, KB, VTB);

  attn_fwd11<<<dim3(32, 16, 2), 256, 0, stream>>>(QB, KB, VTB, Op0, Op1, Lp);
  gemm_o_norm<<<dim3(64, 8), 256, 0, stream>>>(Op0, Op1, Lp, WOB, bo, Of);
}

// Round 16
// 115.412 us; speedup vs baseline: 1.0177x; 1.0177x over previous
//
#include <hip/hip_runtime.h>
#include <stdint.h>

typedef short short8 __attribute__((ext_vector_type(8)));
typedef float f32x4 __attribute__((ext_vector_type(4)));
typedef float f32x16 __attribute__((ext_vector_type(16)));
typedef unsigned int uint2v __attribute__((ext_vector_type(2)));
typedef unsigned int uint4v __attribute__((ext_vector_type(4)));

#define SEQ 2048
#define NBH 32   // B*H

__device__ __forceinline__ unsigned short f32_to_bf16(float f) {
  union { float f; uint32_t u; } v; v.f = f;
  return (unsigned short)((v.u + 0x7fffu + ((v.u >> 16) & 1u)) >> 16);
}

__device__ __forceinline__ float bf16_to_f32(unsigned short u) {
  union { uint32_t u; float f; } v; v.u = ((uint32_t)u) << 16;
  return v.f;
}

__device__ __forceinline__ unsigned int cvtpk_bf16(float lo, float hi) {
  unsigned int r;
  asm("v_cvt_pk_bf16_f32 %0, %1, %2" : "=v"(r) : "v"(lo), "v"(hi));
  return r;
}

__device__ __forceinline__ void gload_lds16(const unsigned short* g, unsigned short* l) {
  __builtin_amdgcn_global_load_lds(
      (const __attribute__((address_space(1))) unsigned int*)g,
      (__attribute__((address_space(3))) unsigned int*)l, 16, 0, 0);
}

// One launch casts x AND all four weight matrices: XB, WQB, WKB, WVB, WOB are
// contiguous in ws, so the destination index is just g.
__global__ void cast_all(const float* __restrict__ x,
                         const float* __restrict__ Wq, const float* __restrict__ Wk,
                         const float* __restrict__ Wv, const float* __restrict__ Wo,
                         unsigned short* __restrict__ ws0) {
  int g = blockIdx.x * blockDim.x + threadIdx.x;   // 0..2097151
  int wi = g >> 18, gl = g & 262143;
  const float* src; int off;
  if (wi < 4)      { src = x;  off = g;  }
  else if (wi == 4){ src = Wq; off = gl; }
  else if (wi == 5){ src = Wk; off = gl; }
  else if (wi == 6){ src = Wv; off = gl; }
  else             { src = Wo; off = gl; }
  float4 v = ((const float4*)src)[off];
  ushort4 o;
  o.x = f32_to_bf16(v.x); o.y = f32_to_bf16(v.y);
  o.z = f32_to_bf16(v.z); o.w = f32_to_bf16(v.w);
  ((ushort4*)ws0)[g] = o;
}

// XOR swizzle over the 4 16B-slots of a 64B LDS row: 2-way max bank conflict
#define GSWZ(row, k) ((k) ^ ((row) & 3) ^ (((row) >> 2) & 3))

// C = A(row-major [M][1024]) * B^T (B row-major [N][1024]), 128x128 tile,
// BK=64 (R15: halves the vmcnt(0)+barrier drains vs BK=32 — 32 K-iters, 2
// barriers each; LDS 32KB so occupancy at (256,3) is unchanged; m132's BK=128
// regression was the 64KB-LDS occupancy cliff, avoided here).
// 8-slot row swizzle: LDS[r][t] = G[r][t ^ (r&7)]; fragment read at slot
// u = s*4+lg reads LDS slot u^(r&7). 16 lanes/fragment -> 2 lanes/slot at
// 1024B spacing = same bank = 2-way = free (m136).
// 256 threads = 4 waves (2x2), each wave 64x64 via 4x4 16x16x32 bf16 MFMAs,
// 2 k-steps per LDS tile.
__device__ __forceinline__ void gemm_core_1024(
    const unsigned short* __restrict__ Ag,   // pre-offset to tile-row base
    const unsigned short* __restrict__ Bg,   // pre-offset to tile-col base
    int tid, f32x4 acc[4][4])
{
  __shared__ __align__(16) unsigned short As[128 * 64];
  __shared__ __align__(16) unsigned short Bs[128 * 64];
  const int w = tid >> 6, l = tid & 63;
  const int wr = w >> 1, wc = w & 1;
  const int lc = l & 15, lg = l >> 4;

  // staging: batch j covers rows j*32..j*32+31; thread -> row j*32+(tid>>3),
  // dst slot tid&7, pre-swizzled src slot (tid&7)^(row&7). Wave-uniform LDS
  // base (j*32 + w*8)*64; lanes fill rows w*8..w*8+7 x slots 0..7 linearly.
  const int srow_in = tid >> 3;      // 0..31
  const int sslot = tid & 7;
  int soff[4];
#pragma unroll
  for (int j = 0; j < 4; ++j) {
    int r = j * 32 + srow_in;
    soff[j] = r * 1024 + ((sslot ^ (r & 7)) * 8);
  }

  for (int k0 = 0; k0 < 1024; k0 += 64) {
#pragma unroll
    for (int j = 0; j < 4; ++j) {
      gload_lds16(Ag + soff[j] + k0, As + (j * 32 + w * 8) * 64);
      gload_lds16(Bg + soff[j] + k0, Bs + (j * 32 + w * 8) * 64);
    }
    __syncthreads();

#pragma unroll
    for (int s = 0; s < 2; ++s) {
      short8 a[4], b[4];
#pragma unroll
      for (int mi = 0; mi < 4; ++mi) {
        int row = wr * 64 + mi * 16 + lc;
        a[mi] = *(const short8*)(As + row * 64 + (((s * 4 + lg) ^ (row & 7)) * 8));
      }
#pragma unroll
      for (int ni = 0; ni < 4; ++ni) {
        int row = wc * 64 + ni * 16 + lc;
        b[ni] = *(const short8*)(Bs + row * 64 + (((s * 4 + lg) ^ (row & 7)) * 8));
      }
#pragma unroll
      for (int mi = 0; mi < 4; ++mi)
#pragma unroll
        for (int ni = 0; ni < 4; ++ni)
          acc[mi][ni] = __builtin_amdgcn_mfma_f32_16x16x32_bf16(a[mi], b[ni], acc[mi][ni], 0, 0, 0);
    }
    __syncthreads();
  }
}

// QKV GEMM: A = x_bf16 [4096][1024]; B selected among Wq/Wk/Wv by tile col.
// Q: scaled by log2(e)/32, layout [bh][n][64]. K: [bh][n][64].
// V: written DIRECTLY TRANSPOSED to VT [bh][64 d][2048 n] (vectorized 8B stores).
__global__ __launch_bounds__(256, 3)
void gemm_qkv(const unsigned short* __restrict__ XB,
              const unsigned short* __restrict__ WQB,
              const unsigned short* __restrict__ WKB,
              const unsigned short* __restrict__ WVB,
              const float* __restrict__ bq,
              const float* __restrict__ bk,
              const float* __restrict__ bv,
              unsigned short* __restrict__ Qo,
              unsigned short* __restrict__ Ko,
              unsigned short* __restrict__ VTo)
{
  const int tid = threadIdx.x;
  const int tm = blockIdx.x * 128;
  const int tn = blockIdx.y * 128;            // 0..2944
  const int wi = tn >> 10;
  const int tnl = tn & 1023;
  const unsigned short* Bw = (wi == 0 ? WQB : wi == 1 ? WKB : WVB) + (size_t)tnl * 1024;
  const float* bias = (wi == 0 ? bq : wi == 1 ? bk : bv);
  const float qscale = (wi == 0) ? 0.04508422002778011f : 1.0f;  // log2(e)/32

  f32x4 acc[4][4];
#pragma unroll
  for (int mi = 0; mi < 4; ++mi)
#pragma unroll
    for (int ni = 0; ni < 4; ++ni)
      acc[mi][ni] = (f32x4){0.f, 0.f, 0.f, 0.f};

  gemm_core_1024(XB + (size_t)tm * 1024, Bw, tid, acc);

  const int w = tid >> 6, l = tid & 63;
  const int wr = w >> 1, wc = w & 1;
  const int lc = l & 15, lg = l >> 4;

  if (wi == 2) {
    // V transposed epilogue: 4 consecutive i (r=0..3) pack into one 8B store.
#pragma unroll
    for (int ni = 0; ni < 4; ++ni) {
      int nl = tnl + wc * 64 + ni * 16 + lc;
      float bb = bias[nl];
      int h = nl >> 6, d = nl & 63;
#pragma unroll
      for (int mi = 0; mi < 4; ++mi) {
        int ibase = tm + wr * 64 + mi * 16 + lg * 4;
        int b = ibase >> 11, i = ibase & 2047;
        uint2v pk;
        pk.x = cvtpk_bf16(acc[mi][ni][0] + bb, acc[mi][ni][1] + bb);
        pk.y = cvtpk_bf16(acc[mi][ni][2] + bb, acc[mi][ni][3] + bb);
        *(uint2v*)(VTo + (((size_t)(b * 16 + h) * 64 + d) * SEQ + i)) = pk;
      }
    }
  } else {
    unsigned short* Out = (wi == 0) ? Qo : Ko;
#pragma unroll
    for (int ni = 0; ni < 4; ++ni) {
      int nl = tnl + wc * 64 + ni * 16 + lc;
      float bb = bias[nl];
      int h = nl >> 6, d = nl & 63;
#pragma unroll
      for (int mi = 0; mi < 4; ++mi) {
#pragma unroll
        for (int r = 0; r < 4; ++r) {
          int m = tm + wr * 64 + mi * 16 + lg * 4 + r;
          int b = m >> 11, i = m & 2047;
          float v = (acc[mi][ni][r] + bb) * qscale;
          Out[(((size_t)(b * 16 + h) * SEQ + i) << 6) + d] = f32_to_bf16(v);
        }
      }
    }
  }
}

// O GEMM with fused j-split merge + normalize (R14/R15 state: Lp hoist +
// T14-lite A-prefetch; prefetch measured null but harmless). 64x128 tile,
// grid 64x8 = 512 blocks = 2/CU.
__global__ __launch_bounds__(256, 2)
void gemm_o_norm(const unsigned short* __restrict__ Op0,
                 const unsigned short* __restrict__ Op1,
                 const float* __restrict__ Lp,
                 const unsigned short* __restrict__ WOB,
                 const float* __restrict__ bo,
                 float* __restrict__ Of)
{
  __shared__ __align__(16) unsigned short As[64 * 32];
  __shared__ __align__(16) unsigned short Bs[128 * 32];
  const int tid = threadIdx.x;
  const int w = tid >> 6, l = tid & 63;
  const int lc = l & 15, lg = l >> 4;
  const int tm = blockIdx.x * 64;
  const int tn = blockIdx.y * 128;
  const unsigned short* Bg = WOB + (size_t)tn * 1024;

  const int crow = tid >> 2, cks = tid & 3;
  const int m = tm + crow;
  const int bb_ = m >> 11, ii = m & 2047;
  const int kg = GSWZ(crow, cks);
  const size_t abase = (size_t)m * 1024 + kg * 8;     // elem offset in Op*
  const float* LpA = Lp + (size_t)(bb_ * 16) * SEQ + ii;   // + h*SEQ
  const float* LpB = LpA + (size_t)NBH * SEQ;

  // hoist all 16 per-head inverses (removes per-iter Lp latency + fdiv)
  float inv[16];
#pragma unroll
  for (int hh = 0; hh < 16; ++hh)
    inv[hh] = 1.0f / (LpA[(size_t)hh * SEQ] + LpB[(size_t)hh * SEQ]);

  union AV { uint4v v; unsigned short e[8]; };
  AV A0, A1, A0n, A1n;
  A0.v = *(const uint4v*)(Op0 + abase);        // preload k0 = 0
  A1.v = *(const uint4v*)(Op1 + abase);

  f32x4 acc[4][2];
#pragma unroll
  for (int mi = 0; mi < 4; ++mi)
#pragma unroll
    for (int ni = 0; ni < 2; ++ni)
      acc[mi][ni] = (f32x4){0.f, 0.f, 0.f, 0.f};

  for (int k0 = 0; k0 < 1024; k0 += 32) {
    // B staging (async)
    gload_lds16(Bg + (size_t)crow * 1024 + k0 + kg * 8, Bs + w * 512);
    gload_lds16(Bg + (size_t)(64 + crow) * 1024 + k0 + kg * 8, Bs + 2048 + w * 512);

    // merge + normalize current A regs, write to swizzled LDS slot
    const float iv = inv[k0 >> 6];
    uint4v wv;
    wv.x = cvtpk_bf16((bf16_to_f32(A0.e[0]) + bf16_to_f32(A1.e[0])) * iv,
                      (bf16_to_f32(A0.e[1]) + bf16_to_f32(A1.e[1])) * iv);
    wv.y = cvtpk_bf16((bf16_to_f32(A0.e[2]) + bf16_to_f32(A1.e[2])) * iv,
                      (bf16_to_f32(A0.e[3]) + bf16_to_f32(A1.e[3])) * iv);
    wv.z = cvtpk_bf16((bf16_to_f32(A0.e[4]) + bf16_to_f32(A1.e[4])) * iv,
                      (bf16_to_f32(A0.e[5]) + bf16_to_f32(A1.e[5])) * iv);
    wv.w = cvtpk_bf16((bf16_to_f32(A0.e[6]) + bf16_to_f32(A1.e[6])) * iv,
                      (bf16_to_f32(A0.e[7]) + bf16_to_f32(A1.e[7])) * iv);
    *(uint4v*)(As + crow * 32 + cks * 8) = wv;

    // T14-lite: issue next iter's A loads now
    if (k0 + 32 < 1024) {
      A0n.v = *(const uint4v*)(Op0 + abase + k0 + 32);
      A1n.v = *(const uint4v*)(Op1 + abase + k0 + 32);
    }
    __syncthreads();

    short8 a[4], b[2];
#pragma unroll
    for (int mi = 0; mi < 4; ++mi) {
      int row = mi * 16 + lc;
      a[mi] = *(const short8*)(As + row * 32 + GSWZ(row, lg) * 8);
    }
#pragma unroll
    for (int ni = 0; ni < 2; ++ni) {
      int row = w * 32 + ni * 16 + lc;
      b[ni] = *(const short8*)(Bs + row * 32 + GSWZ(row, lg) * 8);
    }
#pragma unroll
    for (int mi = 0; mi < 4; ++mi)
#pragma unroll
      for (int ni = 0; ni < 2; ++ni)
        acc[mi][ni] = __builtin_amdgcn_mfma_f32_16x16x32_bf16(a[mi], b[ni], acc[mi][ni], 0, 0, 0);
    __syncthreads();
    A0 = A0n; A1 = A1n;
  }

#pragma unroll
  for (int ni = 0; ni < 2; ++ni) {
    int n = tn + w * 32 + ni * 16 + lc;
    float bb = bo[n];
#pragma unroll
    for (int mi = 0; mi < 4; ++mi) {
#pragma unroll
      for (int r = 0; r < 4; ++r) {
        int mm = tm + mi * 16 + lg * 4 + r;
        Of[(size_t)mm * 1024 + n] = acc[mi][ni][r] + bb;
      }
    }
  }
}

// ---------------------------------------------------------------------------
// Flash attention fwd v11 (proven 47.8us; VGPR 64, no spill). Fixed-base
// softmax + j-split, disjoint partial stores; halved pa-build shuffles.
// NOTE: v_permlane32_swap_b32 tried twice (R4/R11) — semantics not as
// modeled; DO NOT USE. __shfl_xor(.,32) is the proven exchange.
// Grid (32 bh, 16 qt, 2 js) = 1024 blocks = 4 blocks/CU = 16 waves/CU.
// ---------------------------------------------------------------------------
__global__ __launch_bounds__(256, 4)
void attn_fwd11(const unsigned short* __restrict__ Qm,
                const unsigned short* __restrict__ Km,
                const unsigned short* __restrict__ VTm,
                unsigned short* __restrict__ Op0,
                unsigned short* __restrict__ Op1,
                float* __restrict__ Lp)
{
  __shared__ __align__(16) unsigned short KV[2][64 * 128];
  const int tid = threadIdx.x, w = tid >> 6, l = tid & 63;
  const int lq = l & 31, hi = l >> 5;
  const int m15 = lq & 15;
  const int bh = blockIdx.x, q0 = blockIdx.y * 128;
  const int js = blockIdx.z;
  const int j0 = js << 10;                   // j-split: 0 or 1024

  const unsigned short* Qb = Qm + ((size_t)bh * SEQ + q0 + w * 32) * 64;
  const unsigned short* Kg = Km + ((size_t)bh * SEQ + j0) * 64;
  const unsigned short* Vg = VTm + (size_t)bh * 64 * SEQ + j0;   // [64 d][j0..]

  // Staging (R3-verified): LDS[r][s] = G[r][s ^ (r&15)], row r = K[j+r]|VT[r].
  const int sr = l >> 4;        // row within 4-row chunk
  const int ss = l & 15;        // 16B slot
  const unsigned short* sp[4];
  int sstep[4];
#pragma unroll
  for (int i = 0; i < 4; ++i) {
    int r = w * 16 + i * 4 + sr;
    int t = ss ^ (i * 4 + sr);                 // (r&15) == i*4+sr
    if (t < 8) { sp[i] = Kg + (size_t)r * 64 + t * 8;          sstep[i] = 64 * 64; }
    else       { sp[i] = Vg + (size_t)r * SEQ + (t - 8) * 8;   sstep[i] = 64; }
  }

  // Q fragments (B-operand): col=q=lane&31, k = d = kc*16 + hi*8 + [0..7]
  short8 qf[4];
#pragma unroll
  for (int kc = 0; kc < 4; ++kc)
    qf[kc] = *(const short8*)(Qb + lq * 64 + kc * 16 + hi * 8);

  f32x16 o0, o1;
#pragma unroll
  for (int r = 0; r < 16; ++r) { o0[r] = 0.f; o1[r] = 0.f; }
  float sm[8];
#pragma unroll
  for (int i = 0; i < 8; ++i) sm[i] = 0.f;

  // prologue: stage tile 0
#pragma unroll
  for (int i = 0; i < 4; ++i) {
    gload_lds16(sp[i], &KV[0][(w * 16 + i * 4) * 128]);
    sp[i] += sstep[i];
  }
  __syncthreads();

  for (int t = 0; t < 16; ++t) {
    const int cur = t & 1;
    if (t + 1 < 16) {
#pragma unroll
      for (int i = 0; i < 4; ++i) {
        gload_lds16(sp[i], &KV[cur ^ 1][(w * 16 + i * 4) * 128]);
        sp[i] += sstep[i];
      }
    }
    const char* Tb = (const char*)(&KV[cur][0]);

    // S^T = K*Q^T (includes /sqrt(f)*log2e): col=q, row=j_local
    f32x16 s0, s1;
#pragma unroll
    for (int r = 0; r < 16; ++r) { s0[r] = 0.f; s1[r] = 0.f; }
    __builtin_amdgcn_s_setprio(1);
#pragma unroll
    for (int kc = 0; kc < 4; ++kc) {
      short8 kf = *(const short8*)(Tb + lq * 256 + (((kc * 2 + hi) ^ m15) << 4));
      s0 = __builtin_amdgcn_mfma_f32_32x32x16_bf16(kf, qf[kc], s0, 0, 0, 0);
    }
#pragma unroll
    for (int kc = 0; kc < 4; ++kc) {
      short8 kf = *(const short8*)(Tb + (32 + lq) * 256 + (((kc * 2 + hi) ^ m15) << 4));
      s1 = __builtin_amdgcn_mfma_f32_32x32x16_bf16(kf, qf[kc], s1, 0, 0, 0);
    }
    __builtin_amdgcn_s_setprio(0);

    // fixed-base softmax: p = 2^s directly (no max, no subtraction)
    float p[32];
#pragma unroll
    for (int r = 0; r < 16; ++r) {
      p[r] = __builtin_amdgcn_exp2f(s0[r]);
      p[16 + r] = __builtin_amdgcn_exp2f(s1[r]);
    }
#pragma unroll
    for (int i = 0; i < 8; ++i)
      sm[i] += (p[i] + p[i + 8]) + (p[i + 16] + p[i + 24]);

    // P -> bf16 B-fragments: pa[ks] holds P[q][ks*16 + hi*8 + 0..7].
    // Halved exchange: send what the partner needs, one shfl per pair.
    short8 pa[4];
#pragma unroll
    for (int ks = 0; ks < 4; ++ks) {
      const int pb = ks * 8;
      unsigned int a0 = cvtpk_bf16(p[pb + 0], p[pb + 1]);
      unsigned int a1 = cvtpk_bf16(p[pb + 2], p[pb + 3]);
      unsigned int b0 = cvtpk_bf16(p[pb + 4], p[pb + 5]);
      unsigned int b1 = cvtpk_bf16(p[pb + 6], p[pb + 7]);
      unsigned int s0v = hi ? a0 : b0;           // partner's need
      unsigned int s1v = hi ? a1 : b1;
      unsigned int r0 = __shfl_xor((int)s0v, 32);
      unsigned int r1 = __shfl_xor((int)s1v, 32);
      union { uint4v u; short8 s; } cvt;
      cvt.u.x = hi ? r0 : a0;   // hi: partner's b0 ; lo: own a0
      cvt.u.y = hi ? r1 : a1;
      cvt.u.z = hi ? b0 : r0;   // hi: own b0 ; lo: partner's a0
      cvt.u.w = hi ? b1 : r1;
      pa[ks] = cvt.s;
    }

    // O^T += VT * P^T: col=q, row=d_local; V slots are 8..15 of each row
    __builtin_amdgcn_s_setprio(1);
#pragma unroll
    for (int ks = 0; ks < 4; ++ks) {
      short8 vf = *(const short8*)(Tb + lq * 256 + (((8 + ks * 2 + hi) ^ m15) << 4));
      o0 = __builtin_amdgcn_mfma_f32_32x32x16_bf16(vf, pa[ks], o0, 0, 0, 0);
    }
#pragma unroll
    for (int ks = 0; ks < 4; ++ks) {
      short8 vf = *(const short8*)(Tb + (32 + lq) * 256 + (((8 + ks * 2 + hi) ^ m15) << 4));
      o1 = __builtin_amdgcn_mfma_f32_32x32x16_bf16(vf, pa[ks], o1, 0, 0, 0);
    }
    __builtin_amdgcn_s_setprio(0);
    __syncthreads();   // drains vmcnt (stage) + lgkm; buffers flip
  }

  // epilogue: vectorized bf16 partial stores into js-private buffer
  float lden = ((sm[0] + sm[1]) + (sm[2] + sm[3])) + ((sm[4] + sm[5]) + (sm[6] + sm[7]));
  lden += __shfl_xor(lden, 32);              // combine hi/lo j-interleave halves
  const int b = bh >> 4, h = bh & 15;
  const int iq = q0 + w * 32 + lq;
  unsigned short* Op = js ? Op1 : Op0;
  if (hi == 0) Lp[(size_t)js * (NBH * SEQ) + (size_t)bh * SEQ + iq] = lden;
  const size_t obase = ((size_t)b * SEQ + iq) * 1024 + h * 64;
#pragma unroll
  for (int rq = 0; rq < 4; ++rq) {
    uint2v pk0, pk1;
    pk0.x = cvtpk_bf16(o0[rq * 4 + 0], o0[rq * 4 + 1]);
    pk0.y = cvtpk_bf16(o0[rq * 4 + 2], o0[rq * 4 + 3]);
    pk1.x = cvtpk_bf16(o1[rq * 4 + 0], o1[rq * 4 + 1]);
    pk1.y = cvtpk_bf16(o1[rq * 4 + 2], o1[rq * 4 + 3]);
    *(uint2v*)(Op + obase + rq * 8 + hi * 4) = pk0;
    *(uint2v*)(Op + obase + 32 + rq * 8 + hi * 4) = pk1;
  }
}

extern "C" void kernel_launch(void* const* d_in, const int* in_sizes, int n_in,
                              void* d_out, int out_size, void* d_ws, size_t ws_size,
                              hipStream_t stream) {
  (void)in_sizes; (void)n_in; (void)out_size; (void)ws_size;
  const float* x  = (const float*)d_in[0];
  const float* Wq = (const float*)d_in[1];
  const float* bq = (const float*)d_in[2];
  const float* Wk = (const float*)d_in[3];
  const float* bk = (const float*)d_in[4];
  const float* Wv = (const float*)d_in[5];
  const float* bv = (const float*)d_in[6];
  const float* Wo = (const float*)d_in[7];
  const float* bo = (const float*)d_in[8];
  float* Of = (float*)d_out;

  // ws layout (bf16-elem offsets); total 58,720,256 bytes.
  // Aliases (dead regions by attn time): Op0 over XB, Op1 right before VTB,
  // Lp over WQB. V is written directly transposed into VTB by gemm_qkv.
  unsigned short* ws  = (unsigned short*)d_ws;
  unsigned short* XB  = ws;               // x bf16 [4096][1024]
  unsigned short* WQB = ws + 4194304u;    // W casts contiguous: WQB,WKB,WVB,WOB
  unsigned short* WKB = ws + 5242880u;
  unsigned short* WVB = ws + 6291456u;
  unsigned short* WOB = ws + 7340032u;
  unsigned short* QB  = ws + 8388608u;    // [32][2048][64]
  unsigned short* KB  = ws + 12582912u;
  unsigned short* VTB = ws + 20971520u;   // [32][64][2048]
  unsigned short* Op0 = ws;               // [4096][1024] bf16 (js=0, over XB)
  unsigned short* Op1 = ws + 16777216u;   // [4096][1024] bf16 (js=1)
  float* Lp = (float*)(ws + 4194304u);    // [2][32][2048] f32 (over WQB)

  cast_all<<<8192, 256, 0, stream>>>(x, Wq, Wk, Wv, Wo, ws);

  gemm_qkv<<<dim3(32, 24), 256, 0, stream>>>(XB, WQB, WKB, WVB, bq, bk, bv, QB, KB, VTB);

  attn_fwd11<<<dim3(32, 16, 2), 256, 0, stream>>>(QB, KB, VTB, Op0, Op1, Lp);
  gemm_o_norm<<<dim3(64, 8), 256, 0, stream>>>(Op0, Op1, Lp, WOB, bo, Of);
}

// Round 17
// 113.381 us; speedup vs baseline: 1.0359x; 1.0179x over previous
//
#include <hip/hip_runtime.h>
#include <stdint.h>

typedef short short8 __attribute__((ext_vector_type(8)));
typedef float f32x4 __attribute__((ext_vector_type(4)));
typedef float f32x16 __attribute__((ext_vector_type(16)));
typedef unsigned int uint2v __attribute__((ext_vector_type(2)));
typedef unsigned int uint4v __attribute__((ext_vector_type(4)));

#define SEQ 2048
#define NBH 32   // B*H

__device__ __forceinline__ unsigned short f32_to_bf16(float f) {
  union { float f; uint32_t u; } v; v.f = f;
  return (unsigned short)((v.u + 0x7fffu + ((v.u >> 16) & 1u)) >> 16);
}

__device__ __forceinline__ float bf16_to_f32(unsigned short u) {
  union { uint32_t u; float f; } v; v.u = ((uint32_t)u) << 16;
  return v.f;
}

__device__ __forceinline__ unsigned int cvtpk_bf16(float lo, float hi) {
  unsigned int r;
  asm("v_cvt_pk_bf16_f32 %0, %1, %2" : "=v"(r) : "v"(lo), "v"(hi));
  return r;
}

__device__ __forceinline__ void gload_lds16(const unsigned short* g, unsigned short* l) {
  __builtin_amdgcn_global_load_lds(
      (const __attribute__((address_space(1))) unsigned int*)g,
      (__attribute__((address_space(3))) unsigned int*)l, 16, 0, 0);
}

// One launch casts x AND all four weight matrices: XB, WQB, WKB, WVB, WOB are
// contiguous in ws, so the destination index is just g.
__global__ void cast_all(const float* __restrict__ x,
                         const float* __restrict__ Wq, const float* __restrict__ Wk,
                         const float* __restrict__ Wv, const float* __restrict__ Wo,
                         unsigned short* __restrict__ ws0) {
  int g = blockIdx.x * blockDim.x + threadIdx.x;   // 0..2097151
  int wi = g >> 18, gl = g & 262143;
  const float* src; int off;
  if (wi < 4)      { src = x;  off = g;  }
  else if (wi == 4){ src = Wq; off = gl; }
  else if (wi == 5){ src = Wk; off = gl; }
  else if (wi == 6){ src = Wv; off = gl; }
  else             { src = Wo; off = gl; }
  float4 v = ((const float4*)src)[off];
  ushort4 o;
  o.x = f32_to_bf16(v.x); o.y = f32_to_bf16(v.y);
  o.z = f32_to_bf16(v.z); o.w = f32_to_bf16(v.w);
  ((ushort4*)ws0)[g] = o;
}

// XOR swizzle over the 4 16B-slots of a 64B LDS row: 2-way max bank conflict
#define GSWZ(row, k) ((k) ^ ((row) & 3) ^ (((row) >> 2) & 3))

// C = A(row-major [M][1024]) * B^T (B row-major [N][1024]), 128x128 tile,
// BK=64 (R15-proven: halves barrier drains; LDS 32KB, (256,3) occupancy).
// 8-slot row swizzle: LDS[r][t] = G[r][t ^ (r&7)]; fragment read at slot
// u = s*4+lg reads LDS slot u^(r&7). 2 lanes/slot = free (m136).
__device__ __forceinline__ void gemm_core_1024(
    const unsigned short* __restrict__ Ag,   // pre-offset to tile-row base
    const unsigned short* __restrict__ Bg,   // pre-offset to tile-col base
    int tid, f32x4 acc[4][4])
{
  __shared__ __align__(16) unsigned short As[128 * 64];
  __shared__ __align__(16) unsigned short Bs[128 * 64];
  const int w = tid >> 6, l = tid & 63;
  const int wr = w >> 1, wc = w & 1;
  const int lc = l & 15, lg = l >> 4;

  const int srow_in = tid >> 3;      // 0..31
  const int sslot = tid & 7;
  int soff[4];
#pragma unroll
  for (int j = 0; j < 4; ++j) {
    int r = j * 32 + srow_in;
    soff[j] = r * 1024 + ((sslot ^ (r & 7)) * 8);
  }

  for (int k0 = 0; k0 < 1024; k0 += 64) {
#pragma unroll
    for (int j = 0; j < 4; ++j) {
      gload_lds16(Ag + soff[j] + k0, As + (j * 32 + w * 8) * 64);
      gload_lds16(Bg + soff[j] + k0, Bs + (j * 32 + w * 8) * 64);
    }
    __syncthreads();

#pragma unroll
    for (int s = 0; s < 2; ++s) {
      short8 a[4], b[4];
#pragma unroll
      for (int mi = 0; mi < 4; ++mi) {
        int row = wr * 64 + mi * 16 + lc;
        a[mi] = *(const short8*)(As + row * 64 + (((s * 4 + lg) ^ (row & 7)) * 8));
      }
#pragma unroll
      for (int ni = 0; ni < 4; ++ni) {
        int row = wc * 64 + ni * 16 + lc;
        b[ni] = *(const short8*)(Bs + row * 64 + (((s * 4 + lg) ^ (row & 7)) * 8));
      }
#pragma unroll
      for (int mi = 0; mi < 4; ++mi)
#pragma unroll
        for (int ni = 0; ni < 4; ++ni)
          acc[mi][ni] = __builtin_amdgcn_mfma_f32_16x16x32_bf16(a[mi], b[ni], acc[mi][ni], 0, 0, 0);
    }
    __syncthreads();
  }
}

// QKV GEMM: A = x_bf16 [4096][1024]; B selected among Wq/Wk/Wv by tile col.
// Q: scaled by log2(e)/32, layout [bh][n][64]. K: [bh][n][64].
// V: written DIRECTLY TRANSPOSED to VT [bh][64 d][2048 n] (vectorized 8B stores).
__global__ __launch_bounds__(256, 3)
void gemm_qkv(const unsigned short* __restrict__ XB,
              const unsigned short* __restrict__ WQB,
              const unsigned short* __restrict__ WKB,
              const unsigned short* __restrict__ WVB,
              const float* __restrict__ bq,
              const float* __restrict__ bk,
              const float* __restrict__ bv,
              unsigned short* __restrict__ Qo,
              unsigned short* __restrict__ Ko,
              unsigned short* __restrict__ VTo)
{
  const int tid = threadIdx.x;
  const int tm = blockIdx.x * 128;
  const int tn = blockIdx.y * 128;            // 0..2944
  const int wi = tn >> 10;
  const int tnl = tn & 1023;
  const unsigned short* Bw = (wi == 0 ? WQB : wi == 1 ? WKB : WVB) + (size_t)tnl * 1024;
  const float* bias = (wi == 0 ? bq : wi == 1 ? bk : bv);
  const float qscale = (wi == 0) ? 0.04508422002778011f : 1.0f;  // log2(e)/32

  f32x4 acc[4][4];
#pragma unroll
  for (int mi = 0; mi < 4; ++mi)
#pragma unroll
    for (int ni = 0; ni < 4; ++ni)
      acc[mi][ni] = (f32x4){0.f, 0.f, 0.f, 0.f};

  gemm_core_1024(XB + (size_t)tm * 1024, Bw, tid, acc);

  const int w = tid >> 6, l = tid & 63;
  const int wr = w >> 1, wc = w & 1;
  const int lc = l & 15, lg = l >> 4;

  if (wi == 2) {
    // V transposed epilogue: 4 consecutive i (r=0..3) pack into one 8B store.
#pragma unroll
    for (int ni = 0; ni < 4; ++ni) {
      int nl = tnl + wc * 64 + ni * 16 + lc;
      float bb = bias[nl];
      int h = nl >> 6, d = nl & 63;
#pragma unroll
      for (int mi = 0; mi < 4; ++mi) {
        int ibase = tm + wr * 64 + mi * 16 + lg * 4;
        int b = ibase >> 11, i = ibase & 2047;
        uint2v pk;
        pk.x = cvtpk_bf16(acc[mi][ni][0] + bb, acc[mi][ni][1] + bb);
        pk.y = cvtpk_bf16(acc[mi][ni][2] + bb, acc[mi][ni][3] + bb);
        *(uint2v*)(VTo + (((size_t)(b * 16 + h) * 64 + d) * SEQ + i)) = pk;
      }
    }
  } else {
    unsigned short* Out = (wi == 0) ? Qo : Ko;
#pragma unroll
    for (int ni = 0; ni < 4; ++ni) {
      int nl = tnl + wc * 64 + ni * 16 + lc;
      float bb = bias[nl];
      int h = nl >> 6, d = nl & 63;
#pragma unroll
      for (int mi = 0; mi < 4; ++mi) {
#pragma unroll
        for (int r = 0; r < 4; ++r) {
          int m = tm + wr * 64 + mi * 16 + lg * 4 + r;
          int b = m >> 11, i = m & 2047;
          float v = (acc[mi][ni][r] + bb) * qscale;
          Out[(((size_t)(b * 16 + h) * SEQ + i) << 6) + d] = f32_to_bf16(v);
        }
      }
    }
  }
}

// O GEMM with fused j-split merge + normalize, BK=64 (R16: mirror of the
// R15-proven qkv win — 16 iters x 2 barriers instead of 32 x 2).
// B: [128][64] LDS staged via pre-swizzled-source gload_lds (same soff math
// as gemm_core_1024). A: [64][64]; each thread owns row tid>>2, two 8-elem
// slots {s0, s0+4}; merge (Op0+Op1)*inv in regs and ds_write to LDS slot
// s^(row&7)  => same LDS[r][t]=G[r][t^(r&7)] relation as B. Row stride 128B
// -> bank = f(slot), 8 lanes per 4-bank group = LDS write BW, conflict-free.
// BK=64 == one head per iter (inv[k0>>6]). A next-iter prefetch kept.
__global__ __launch_bounds__(256, 2)
void gemm_o_norm(const unsigned short* __restrict__ Op0,
                 const unsigned short* __restrict__ Op1,
                 const float* __restrict__ Lp,
                 const unsigned short* __restrict__ WOB,
                 const float* __restrict__ bo,
                 float* __restrict__ Of)
{
  __shared__ __align__(16) unsigned short As[64 * 64];
  __shared__ __align__(16) unsigned short Bs[128 * 64];
  const int tid = threadIdx.x;
  const int w = tid >> 6, l = tid & 63;
  const int lc = l & 15, lg = l >> 4;
  const int tm = blockIdx.x * 64;
  const int tn = blockIdx.y * 128;
  const unsigned short* Bg = WOB + (size_t)tn * 1024;

  // B staging offsets (identical pattern to gemm_core_1024)
  const int srow_in = tid >> 3, sslot = tid & 7;
  int soffB[4];
#pragma unroll
  for (int j = 0; j < 4; ++j) {
    int r = j * 32 + srow_in;
    soffB[j] = r * 1024 + ((sslot ^ (r & 7)) * 8);
  }

  // A ownership: row = tid>>2 (0..63), slots s0 and s0+4
  const int arow = tid >> 2, s0 = tid & 3;
  const int m = tm + arow;
  const int bb_ = m >> 11, ii = m & 2047;
  const size_t abase = (size_t)m * 1024;
  const int t0 = (s0 ^ (arow & 7)) * 8;          // LDS dest slots (swizzled)
  const int t1 = ((s0 + 4) ^ (arow & 7)) * 8;
  const float* LpA = Lp + (size_t)(bb_ * 16) * SEQ + ii;   // + h*SEQ
  const float* LpB = LpA + (size_t)NBH * SEQ;

  // hoist all 16 per-head inverses
  float inv[16];
#pragma unroll
  for (int hh = 0; hh < 16; ++hh)
    inv[hh] = 1.0f / (LpA[(size_t)hh * SEQ] + LpB[(size_t)hh * SEQ]);

  union AV { uint4v v; unsigned short e[8]; };
  AV A00, A01, A10, A11, N00, N01, N10, N11;
  A00.v = *(const uint4v*)(Op0 + abase + s0 * 8);
  A01.v = *(const uint4v*)(Op1 + abase + s0 * 8);
  A10.v = *(const uint4v*)(Op0 + abase + (s0 + 4) * 8);
  A11.v = *(const uint4v*)(Op1 + abase + (s0 + 4) * 8);

  f32x4 acc[4][2];
#pragma unroll
  for (int mi = 0; mi < 4; ++mi)
#pragma unroll
    for (int ni = 0; ni < 2; ++ni)
      acc[mi][ni] = (f32x4){0.f, 0.f, 0.f, 0.f};

  for (int k0 = 0; k0 < 1024; k0 += 64) {
    // B staging (async)
#pragma unroll
    for (int j = 0; j < 4; ++j)
      gload_lds16(Bg + soffB[j] + k0, Bs + (j * 32 + w * 8) * 64);

    // A: merge + normalize, two swizzled b128 LDS writes
    const float iv = inv[k0 >> 6];
    uint4v wv0, wv1;
    wv0.x = cvtpk_bf16((bf16_to_f32(A00.e[0]) + bf16_to_f32(A01.e[0])) * iv,
                       (bf16_to_f32(A00.e[1]) + bf16_to_f32(A01.e[1])) * iv);
    wv0.y = cvtpk_bf16((bf16_to_f32(A00.e[2]) + bf16_to_f32(A01.e[2])) * iv,
                       (bf16_to_f32(A00.e[3]) + bf16_to_f32(A01.e[3])) * iv);
    wv0.z = cvtpk_bf16((bf16_to_f32(A00.e[4]) + bf16_to_f32(A01.e[4])) * iv,
                       (bf16_to_f32(A00.e[5]) + bf16_to_f32(A01.e[5])) * iv);
    wv0.w = cvtpk_bf16((bf16_to_f32(A00.e[6]) + bf16_to_f32(A01.e[6])) * iv,
                       (bf16_to_f32(A00.e[7]) + bf16_to_f32(A01.e[7])) * iv);
    wv1.x = cvtpk_bf16((bf16_to_f32(A10.e[0]) + bf16_to_f32(A11.e[0])) * iv,
                       (bf16_to_f32(A10.e[1]) + bf16_to_f32(A11.e[1])) * iv);
    wv1.y = cvtpk_bf16((bf16_to_f32(A10.e[2]) + bf16_to_f32(A11.e[2])) * iv,
                       (bf16_to_f32(A10.e[3]) + bf16_to_f32(A11.e[3])) * iv);
    wv1.z = cvtpk_bf16((bf16_to_f32(A10.e[4]) + bf16_to_f32(A11.e[4])) * iv,
                       (bf16_to_f32(A10.e[5]) + bf16_to_f32(A11.e[5])) * iv);
    wv1.w = cvtpk_bf16((bf16_to_f32(A10.e[6]) + bf16_to_f32(A11.e[6])) * iv,
                       (bf16_to_f32(A10.e[7]) + bf16_to_f32(A11.e[7])) * iv);
    *(uint4v*)(As + arow * 64 + t0) = wv0;
    *(uint4v*)(As + arow * 64 + t1) = wv1;

    // prefetch next iter's A (hides under barrier + fragment reads + MFMA)
    if (k0 + 64 < 1024) {
      N00.v = *(const uint4v*)(Op0 + abase + k0 + 64 + s0 * 8);
      N01.v = *(const uint4v*)(Op1 + abase + k0 + 64 + s0 * 8);
      N10.v = *(const uint4v*)(Op0 + abase + k0 + 64 + (s0 + 4) * 8);
      N11.v = *(const uint4v*)(Op1 + abase + k0 + 64 + (s0 + 4) * 8);
    }
    __syncthreads();

#pragma unroll
    for (int s = 0; s < 2; ++s) {
      short8 a[4], b[2];
#pragma unroll
      for (int mi = 0; mi < 4; ++mi) {
        int row = mi * 16 + lc;
        a[mi] = *(const short8*)(As + row * 64 + (((s * 4 + lg) ^ (row & 7)) * 8));
      }
#pragma unroll
      for (int ni = 0; ni < 2; ++ni) {
        int row = w * 32 + ni * 16 + lc;
        b[ni] = *(const short8*)(Bs + row * 64 + (((s * 4 + lg) ^ (row & 7)) * 8));
      }
#pragma unroll
      for (int mi = 0; mi < 4; ++mi)
#pragma unroll
        for (int ni = 0; ni < 2; ++ni)
          acc[mi][ni] = __builtin_amdgcn_mfma_f32_16x16x32_bf16(a[mi], b[ni], acc[mi][ni], 0, 0, 0);
    }
    __syncthreads();
    A00 = N00; A01 = N01; A10 = N10; A11 = N11;
  }

#pragma unroll
  for (int ni = 0; ni < 2; ++ni) {
    int n = tn + w * 32 + ni * 16 + lc;
    float bb = bo[n];
#pragma unroll
    for (int mi = 0; mi < 4; ++mi) {
#pragma unroll
      for (int r = 0; r < 4; ++r) {
        int mm = tm + mi * 16 + lg * 4 + r;
        Of[(size_t)mm * 1024 + n] = acc[mi][ni][r] + bb;
      }
    }
  }
}

// ---------------------------------------------------------------------------
// Flash attention fwd v11 (proven 47.8us; VGPR 64, no spill). Fixed-base
// softmax + j-split, disjoint partial stores; halved pa-build shuffles.
// NOTE: v_permlane32_swap_b32 tried twice (R4/R11) — semantics not as
// modeled; DO NOT USE. __shfl_xor(.,32) is the proven exchange.
// Grid (32 bh, 16 qt, 2 js) = 1024 blocks = 4 blocks/CU = 16 waves/CU.
// ---------------------------------------------------------------------------
__global__ __launch_bounds__(256, 4)
void attn_fwd11(const unsigned short* __restrict__ Qm,
                const unsigned short* __restrict__ Km,
                const unsigned short* __restrict__ VTm,
                unsigned short* __restrict__ Op0,
                unsigned short* __restrict__ Op1,
                float* __restrict__ Lp)
{
  __shared__ __align__(16) unsigned short KV[2][64 * 128];
  const int tid = threadIdx.x, w = tid >> 6, l = tid & 63;
  const int lq = l & 31, hi = l >> 5;
  const int m15 = lq & 15;
  const int bh = blockIdx.x, q0 = blockIdx.y * 128;
  const int js = blockIdx.z;
  const int j0 = js << 10;                   // j-split: 0 or 1024

  const unsigned short* Qb = Qm + ((size_t)bh * SEQ + q0 + w * 32) * 64;
  const unsigned short* Kg = Km + ((size_t)bh * SEQ + j0) * 64;
  const unsigned short* Vg = VTm + (size_t)bh * 64 * SEQ + j0;   // [64 d][j0..]

  // Staging (R3-verified): LDS[r][s] = G[r][s ^ (r&15)], row r = K[j+r]|VT[r].
  const int sr = l >> 4;        // row within 4-row chunk
  const int ss = l & 15;        // 16B slot
  const unsigned short* sp[4];
  int sstep[4];
#pragma unroll
  for (int i = 0; i < 4; ++i) {
    int r = w * 16 + i * 4 + sr;
    int t = ss ^ (i * 4 + sr);                 // (r&15) == i*4+sr
    if (t < 8) { sp[i] = Kg + (size_t)r * 64 + t * 8;          sstep[i] = 64 * 64; }
    else       { sp[i] = Vg + (size_t)r * SEQ + (t - 8) * 8;   sstep[i] = 64; }
  }

  // Q fragments (B-operand): col=q=lane&31, k = d = kc*16 + hi*8 + [0..7]
  short8 qf[4];
#pragma unroll
  for (int kc = 0; kc < 4; ++kc)
    qf[kc] = *(const short8*)(Qb + lq * 64 + kc * 16 + hi * 8);

  f32x16 o0, o1;
#pragma unroll
  for (int r = 0; r < 16; ++r) { o0[r] = 0.f; o1[r] = 0.f; }
  float sm[8];
#pragma unroll
  for (int i = 0; i < 8; ++i) sm[i] = 0.f;

  // prologue: stage tile 0
#pragma unroll
  for (int i = 0; i < 4; ++i) {
    gload_lds16(sp[i], &KV[0][(w * 16 + i * 4) * 128]);
    sp[i] += sstep[i];
  }
  __syncthreads();

  for (int t = 0; t < 16; ++t) {
    const int cur = t & 1;
    if (t + 1 < 16) {
#pragma unroll
      for (int i = 0; i < 4; ++i) {
        gload_lds16(sp[i], &KV[cur ^ 1][(w * 16 + i * 4) * 128]);
        sp[i] += sstep[i];
      }
    }
    const char* Tb = (const char*)(&KV[cur][0]);

    // S^T = K*Q^T (includes /sqrt(f)*log2e): col=q, row=j_local
    f32x16 s0, s1;
#pragma unroll
    for (int r = 0; r < 16; ++r) { s0[r] = 0.f; s1[r] = 0.f; }
    __builtin_amdgcn_s_setprio(1);
#pragma unroll
    for (int kc = 0; kc < 4; ++kc) {
      short8 kf = *(const short8*)(Tb + lq * 256 + (((kc * 2 + hi) ^ m15) << 4));
      s0 = __builtin_amdgcn_mfma_f32_32x32x16_bf16(kf, qf[kc], s0, 0, 0, 0);
    }
#pragma unroll
    for (int kc = 0; kc < 4; ++kc) {
      short8 kf = *(const short8*)(Tb + (32 + lq) * 256 + (((kc * 2 + hi) ^ m15) << 4));
      s1 = __builtin_amdgcn_mfma_f32_32x32x16_bf16(kf, qf[kc], s1, 0, 0, 0);
    }
    __builtin_amdgcn_s_setprio(0);

    // fixed-base softmax: p = 2^s directly (no max, no subtraction)
    float p[32];
#pragma unroll
    for (int r = 0; r < 16; ++r) {
      p[r] = __builtin_amdgcn_exp2f(s0[r]);
      p[16 + r] = __builtin_amdgcn_exp2f(s1[r]);
    }
#pragma unroll
    for (int i = 0; i < 8; ++i)
      sm[i] += (p[i] + p[i + 8]) + (p[i + 16] + p[i + 24]);

    // P -> bf16 B-fragments: pa[ks] holds P[q][ks*16 + hi*8 + 0..7].
    // Halved exchange: send what the partner needs, one shfl per pair.
    short8 pa[4];
#pragma unroll
    for (int ks = 0; ks < 4; ++ks) {
      const int pb = ks * 8;
      unsigned int a0 = cvtpk_bf16(p[pb + 0], p[pb + 1]);
      unsigned int a1 = cvtpk_bf16(p[pb + 2], p[pb + 3]);
      unsigned int b0 = cvtpk_bf16(p[pb + 4], p[pb + 5]);
      unsigned int b1 = cvtpk_bf16(p[pb + 6], p[pb + 7]);
      unsigned int s0v = hi ? a0 : b0;           // partner's need
      unsigned int s1v = hi ? a1 : b1;
      unsigned int r0 = __shfl_xor((int)s0v, 32);
      unsigned int r1 = __shfl_xor((int)s1v, 32);
      union { uint4v u; short8 s; } cvt;
      cvt.u.x = hi ? r0 : a0;   // hi: partner's b0 ; lo: own a0
      cvt.u.y = hi ? r1 : a1;
      cvt.u.z = hi ? b0 : r0;   // hi: own b0 ; lo: partner's a0
      cvt.u.w = hi ? b1 : r1;
      pa[ks] = cvt.s;
    }

    // O^T += VT * P^T: col=q, row=d_local; V slots are 8..15 of each row
    __builtin_amdgcn_s_setprio(1);
#pragma unroll
    for (int ks = 0; ks < 4; ++ks) {
      short8 vf = *(const short8*)(Tb + lq * 256 + (((8 + ks * 2 + hi) ^ m15) << 4));
      o0 = __builtin_amdgcn_mfma_f32_32x32x16_bf16(vf, pa[ks], o0, 0, 0, 0);
    }
#pragma unroll
    for (int ks = 0; ks < 4; ++ks) {
      short8 vf = *(const short8*)(Tb + (32 + lq) * 256 + (((8 + ks * 2 + hi) ^ m15) << 4));
      o1 = __builtin_amdgcn_mfma_f32_32x32x16_bf16(vf, pa[ks], o1, 0, 0, 0);
    }
    __builtin_amdgcn_s_setprio(0);
    __syncthreads();   // drains vmcnt (stage) + lgkm; buffers flip
  }

  // epilogue: vectorized bf16 partial stores into js-private buffer
  float lden = ((sm[0] + sm[1]) + (sm[2] + sm[3])) + ((sm[4] + sm[5]) + (sm[6] + sm[7]));
  lden += __shfl_xor(lden, 32);              // combine hi/lo j-interleave halves
  const int b = bh >> 4, h = bh & 15;
  const int iq = q0 + w * 32 + lq;
  unsigned short* Op = js ? Op1 : Op0;
  if (hi == 0) Lp[(size_t)js * (NBH * SEQ) + (size_t)bh * SEQ + iq] = lden;
  const size_t obase = ((size_t)b * SEQ + iq) * 1024 + h * 64;
#pragma unroll
  for (int rq = 0; rq < 4; ++rq) {
    uint2v pk0, pk1;
    pk0.x = cvtpk_bf16(o0[rq * 4 + 0], o0[rq * 4 + 1]);
    pk0.y = cvtpk_bf16(o0[rq * 4 + 2], o0[rq * 4 + 3]);
    pk1.x = cvtpk_bf16(o1[rq * 4 + 0], o1[rq * 4 + 1]);
    pk1.y = cvtpk_bf16(o1[rq * 4 + 2], o1[rq * 4 + 3]);
    *(uint2v*)(Op + obase + rq * 8 + hi * 4) = pk0;
    *(uint2v*)(Op + obase + 32 + rq * 8 + hi * 4) = pk1;
  }
}

extern "C" void kernel_launch(void* const* d_in, const int* in_sizes, int n_in,
                              void* d_out, int out_size, void* d_ws, size_t ws_size,
                              hipStream_t stream) {
  (void)in_sizes; (void)n_in; (void)out_size; (void)ws_size;
  const float* x  = (const float*)d_in[0];
  const float* Wq = (const float*)d_in[1];
  const float* bq = (const float*)d_in[2];
  const float* Wk = (const float*)d_in[3];
  const float* bk = (const float*)d_in[4];
  const float* Wv = (const float*)d_in[5];
  const float* bv = (const float*)d_in[6];
  const float* Wo = (const float*)d_in[7];
  const float* bo = (const float*)d_in[8];
  float* Of = (float*)d_out;

  // ws layout (bf16-elem offsets); total 58,720,256 bytes.
  // Aliases (dead regions by attn time): Op0 over XB, Op1 right before VTB,
  // Lp over WQB. V is written directly transposed into VTB by gemm_qkv.
  unsigned short* ws  = (unsigned short*)d_ws;
  unsigned short* XB  = ws;               // x bf16 [4096][1024]
  unsigned short* WQB = ws + 4194304u;    // W casts contiguous: WQB,WKB,WVB,WOB
  unsigned short* WKB = ws + 5242880u;
  unsigned short* WVB = ws + 6291456u;
  unsigned short* WOB = ws + 7340032u;
  unsigned short* QB  = ws + 8388608u;    // [32][2048][64]
  unsigned short* KB  = ws + 12582912u;
  unsigned short* VTB = ws + 20971520u;   // [32][64][2048]
  unsigned short* Op0 = ws;               // [4096][1024] bf16 (js=0, over XB)
  unsigned short* Op1 = ws + 16777216u;   // [4096][1024] bf16 (js=1)
  float* Lp = (float*)(ws + 4194304u);    // [2][32][2048] f32 (over WQB)

  cast_all<<<8192, 256, 0, stream>>>(x, Wq, Wk, Wv, Wo, ws);

  gemm_qkv<<<dim3(32, 24), 256, 0, stream>>>(XB, WQB, WKB, WVB, bq, bk, bv, QB, KB, VTB);

  attn_fwd11<<<dim3(32, 16, 2), 256, 0, stream>>>(QB, KB, VTB, Op0, Op1, Lp);
  gemm_o_norm<<<dim3(64, 8), 256, 0, stream>>>(Op0, Op1, Lp, WOB, bo, Of);
}